// Round 6
// baseline (312.711 us; speedup 1.0000x reference)
//
#include <hip/hip_runtime.h>
#include <hip/hip_bf16.h>
#include <math.h>

// Problem constants (S=1024, B=2 -> T=2048)
#define T_  2048
#define H_  1024
#define F_  4096
#define E_  4
#define EF_ (E_*F_)
#define ROWCAP 4608   // sum_e ceil(cnt_e/128)*128 <= 4096 + 4*127 = 4604
#define KSPLIT 4      // gemm2 split-K slices
#define KS (F_/KSPLIT)

typedef __attribute__((ext_vector_type(8)))  short short8;   // 8 bf16 = 4 VGPRs
typedef __attribute__((ext_vector_type(16))) float f32x16;   // MFMA 32x32 accumulator

#define BM 128
#define BN 128
#define BK 64

// gemm1 8-phase geometry
#define BM1 256
#define BN1 256
#define NT1 16        // H_/BK

#define VMW2()  asm volatile("s_waitcnt vmcnt(2)" ::: "memory")
#define VMW0()  asm volatile("s_waitcnt vmcnt(0)" ::: "memory")
#define LGKM0() asm volatile("s_waitcnt lgkmcnt(0)" ::: "memory")
#define SBAR()  do { __builtin_amdgcn_s_barrier(); __builtin_amdgcn_sched_barrier(0); } while (0)
#define SCHED0() __builtin_amdgcn_sched_barrier(0)

__device__ __forceinline__ void async_copy16(const void* g, void* l) {
    __builtin_amdgcn_global_load_lds(
        (const __attribute__((address_space(1))) void*)g,
        (__attribute__((address_space(3))) void*)l, 16, 0, 0);
}

__device__ __forceinline__ float bf2f(unsigned short u) {
    return __uint_as_float(((unsigned)u) << 16);
}
__device__ __forceinline__ short f2bf_bits(float f) {
    __hip_bfloat16 b = __float2bfloat16(f);
    return *(short*)&b;
}

// prep kernel, grid (64,16,5):
//   z<4 : W1 expert z [H][F] fp32 -> w1t[e][f][h] bf16 (64x64 LDS transpose)
//   z==4: X copy-convert fp32->bf16; block (0,0,4) also builds routing lists.
// (W2 transpose lives in the gemm1 launch; only gemm2 needs W2t.)
__global__ __launch_bounds__(256)
void trans_kernel(const float* __restrict__ w1,
                  const float* __restrict__ x,  const float* __restrict__ probs,
                  __hip_bfloat16* __restrict__ w1t,
                  __hip_bfloat16* __restrict__ xb,
                  int* __restrict__ cnt_g, int* __restrict__ off_g,
                  int* __restrict__ list, int* __restrict__ slot) {
    const int z = blockIdx.z;
    const int t = threadIdx.x;

    if (z == E_) {
        // ---- X convert path ----
        const int bid = blockIdx.y * 64 + blockIdx.x;          // 0..1023
        const size_t base = ((size_t)bid * 256 + t) * 8;       // 8 elems/thread
        const float4 v0 = *(const float4*)&x[base];
        const float4 v1 = *(const float4*)&x[base + 4];
        short8 pk;
        pk[0] = f2bf_bits(v0.x); pk[1] = f2bf_bits(v0.y);
        pk[2] = f2bf_bits(v0.z); pk[3] = f2bf_bits(v0.w);
        pk[4] = f2bf_bits(v1.x); pk[5] = f2bf_bits(v1.y);
        pk[6] = f2bf_bits(v1.z); pk[7] = f2bf_bits(v1.w);
        *(short8*)&((short*)xb)[base] = pk;

        // ---- routing (single designated block) ----
        if (blockIdx.x == 0 && blockIdx.y == 0) {
            __shared__ int lcnt[E_];
            if (t < E_) lcnt[t] = 0;
            __syncthreads();
            const int lane = t & 63;
            const unsigned long long below = ((lane == 63) ? ~0ull : ((1ull << (lane + 1)) - 1)) >> 1;
#pragma unroll
            for (int i = 0; i < T_ / 256; i++) {
                const int tok = i * 256 + t;
                const float4 p = *(const float4*)&probs[(size_t)tok * E_];
                const float pv[4] = {p.x, p.y, p.z, p.w};
#pragma unroll
                for (int e = 0; e < E_; e++) {
                    const bool r = pv[e] > 0.0f;
                    const unsigned long long mask = __ballot(r);
                    int base_pos = 0;
                    if (lane == 0) base_pos = atomicAdd(&lcnt[e], __popcll(mask));
                    base_pos = __shfl(base_pos, 0);
                    const int pos = base_pos + (int)__popcll(mask & below);
                    if (r) { list[e * T_ + pos] = tok; slot[tok * E_ + e] = pos; }
                }
            }
            __syncthreads();
            if (t == 0) {
                int acc = 0;
#pragma unroll
                for (int e = 0; e < E_; e++) {
                    off_g[e] = acc; cnt_g[e] = lcnt[e];
                    acc += (lcnt[e] + 127) & ~127;
                }
                off_g[E_] = acc;
            }
        }
        return;
    }

    // ---- W1 transpose path (verified pattern) ----
    __shared__ float tile[64 * 69 + 4];   // tile[c][r] at c*69 + r
    const float* src = w1 + (size_t)z * H_ * F_;
    __hip_bfloat16* dst = w1t + (size_t)z * F_ * H_;
    const int C = F_, dstStride = H_;
    const int r0 = blockIdx.y * 64;   // over H
    const int c0 = blockIdx.x * 64;   // over F
    const int cl = (t & 15) * 4;
#pragma unroll
    for (int p = 0; p < 4; p++) {
        const int rl = (t >> 4) + 16 * p;
        const float4 v = *(const float4*)&src[(size_t)(r0 + rl) * C + (c0 + cl)];
        tile[(cl + 0) * 69 + rl] = v.x;
        tile[(cl + 1) * 69 + rl] = v.y;
        tile[(cl + 2) * 69 + rl] = v.z;
        tile[(cl + 3) * 69 + rl] = v.w;
    }
    __syncthreads();
    const int orow = (t & 7) * 8;
#pragma unroll
    for (int q = 0; q < 2; q++) {
        const int oc = (t >> 3) + 32 * q;
        short8 pk;
#pragma unroll
        for (int j = 0; j < 8; j++)
            pk[j] = f2bf_bits(tile[oc * 69 + orow + j]);
        *(short8*)&((short*)dst)[(size_t)(c0 + oc) * dstStride + r0 + orow] = pk;
    }
}

// =====================================================================
// GEMM1: 256x256 / 8-wave / BK=64, m201-style fine-phase schedule.
// LDS (128 KiB dynamic): buf b at b*64KiB { A [256][64] bf16 (32KB),
// B at +32KB }. Rows 128B = 8 x 16B chunks; chunk c of row r stored at
// c ^ (r&7) (R0/R3-verified conflict-free geometry), via pre-swizzled
// GLOBAL source + linear LDS dest; readers XOR with row&7.
// Per K-tile t: 4 phases, phase q = k-slice q (16 k):
//   [q==0: issue 2 loads of tile t+1; s_waitcnt vmcnt(2)]   <- counted, not 0
//   ds_read_b128 x6 (A fm=0..3, B fn=0..1 at slice q)
//   [q>0: issue 2 loads of tile t+1]
//   s_barrier ; lgkmcnt(0) ; setprio(1) ; 8 MFMA ; setprio(0) ; s_barrier
// Tile t+1's 8 loads are spread 2-per-phase across tile t (T3 interleave);
// vmcnt(2) at the tile boundary keeps 2 loads in flight (T4, never drain).
// =====================================================================
__global__ __launch_bounds__(512, 2)
void gemm1_kernel(const __hip_bfloat16* __restrict__ Xb,
                  const __hip_bfloat16* __restrict__ W1t,
                  const float* __restrict__ probs,
                  const int* __restrict__ cnt, const int* __restrict__ off,
                  const int* __restrict__ list,
                  __hip_bfloat16* __restrict__ Ag,
                  const float* __restrict__ w2,
                  __hip_bfloat16* __restrict__ w2t) {
    extern __shared__ char smem[];           // 128 KiB (union with W2 path)
    const int tid = threadIdx.x;

    if (blockIdx.z >= E_) {
        // ---- fused W2 transpose: [F][H] fp32 -> w2t[e][h][f] bf16 ----
        // z==4 plane: 16x8=128 blocks x 512 thr; 2 tiles per iter x 16 iters.
        const int half = tid >> 8;               // 0..1 (two 256-thread teams)
        const int tt = tid & 255;
        float* tile = (float*)smem + half * (64 * 69 + 8);
#pragma unroll
        for (int it = 0; it < 16; ++it) {
            const int tile_id = ((blockIdx.y * 16 + blockIdx.x) * 16 + it) * 2 + half;
            const int e2 = tile_id >> 10;        // 1024 tiles per expert
            const int rem = tile_id & 1023;
            const int r0 = (rem >> 4) * 64;      // over F (64 tiles)
            const int c0 = (rem & 15) * 64;      // over H (16 tiles)
            const float* src = w2 + (size_t)e2 * F_ * H_;
            __hip_bfloat16* dst = w2t + (size_t)e2 * F_ * H_;  // (r=f,c=h)->dst[c*F_+r]
            const int cl = (tt & 15) * 4;
#pragma unroll
            for (int p = 0; p < 4; p++) {
                const int rl = (tt >> 4) + 16 * p;
                const float4 v = *(const float4*)&src[(size_t)(r0 + rl) * H_ + (c0 + cl)];
                tile[(cl + 0) * 69 + rl] = v.x;
                tile[(cl + 1) * 69 + rl] = v.y;
                tile[(cl + 2) * 69 + rl] = v.z;
                tile[(cl + 3) * 69 + rl] = v.w;
            }
            __syncthreads();
            const int orow = (tt & 7) * 8;
#pragma unroll
            for (int q = 0; q < 2; q++) {
                const int oc = (tt >> 3) + 32 * q;
                short8 pk;
#pragma unroll
                for (int j = 0; j < 8; j++)
                    pk[j] = f2bf_bits(tile[oc * 69 + orow + j]);
                *(short8*)&((short*)dst)[(size_t)(c0 + oc) * F_ + r0 + orow] = pk;
            }
            __syncthreads();
        }
        return;
    }

    const int e  = blockIdx.z;
    const int ce = cnt[e];
    const int m0 = blockIdx.y * BM1;
    if (m0 >= ce) return;
    const int n0 = blockIdx.x * BN1;          // over F
    const int mpad = off[e + 1] - off[e];     // 128-granular; tile is 256 -> guard stores
    const __hip_bfloat16* Bt = W1t + (size_t)e * F_ * H_;

    const int lane = tid & 63, wave = tid >> 6;
    const int wm = (wave >> 2) * 128, wn = (wave & 3) * 64;
    const int l31 = lane & 31, kh5 = lane >> 5, sw = l31 & 7;
    // staging: 8 lanes per 128B row, 64 rows per load-group (512 thr)
    const int lr8 = tid >> 3;                  // row within 64-row group
    const int lcg = ((tid & 7) ^ (lr8 & 7)) * 8;   // pre-swizzled global chunk

    const __hip_bfloat16* aP[4];
    const __hip_bfloat16* bP[4];
#pragma unroll
    for (int j = 0; j < 4; j++) {
        int rr = m0 + j * 64 + lr8;
        if (rr >= ce) rr = ce - 1;             // dup row; stores guarded below
        aP[j] = Xb + (size_t)list[e * T_ + rr] * H_ + lcg;
        bP[j] = Bt + (size_t)(n0 + j * 64 + lr8) * H_ + lcg;
    }

    f32x16 acc[4][2];
#pragma unroll
    for (int fm = 0; fm < 4; fm++)
#pragma unroll
        for (int fn = 0; fn < 2; fn++)
#pragma unroll
            for (int r = 0; r < 16; r++) acc[fm][fn][r] = 0.f;

    // phase q stages load-group q of tile tt into buf bb:
    //   q=0: A rows 0..127 (j=0,1); q=1: A rows 128..255; q=2: B j=0,1; q=3: B j=2,3
#define STG1(tt, qq, bb) do { \
    const int ko_ = (tt) * BK; \
    char* base_ = smem + (bb) * 65536 + ((qq) >= 2 ? 32768 : 0) + ((qq) & 1) * 16384 + (wave) * 1024; \
    const __hip_bfloat16* const* pp_ = ((qq) >= 2) ? bP : aP; \
    const int j0_ = ((qq) & 1) * 2; \
    async_copy16(pp_[j0_] + ko_, base_); \
    async_copy16(pp_[j0_ + 1] + ko_, base_ + 8192); \
} while (0)

    // prologue: stage all of tile 0 (8 loads in flight)
    STG1(0, 0, 0); STG1(0, 1, 0); STG1(0, 2, 0); STG1(0, 3, 0);

    for (int t = 0; t < NT1; ++t) {
        const int b = t & 1;
        const __hip_bfloat16* Ab = (const __hip_bfloat16*)(smem + b * 65536);
        const __hip_bfloat16* Bb = (const __hip_bfloat16*)(smem + b * 65536 + 32768);
        const bool pre = (t + 1 < NT1);
#pragma unroll
        for (int q = 0; q < 4; q++) {
            if (q == 0) {
                if (pre) { STG1(t + 1, 0, b ^ 1); VMW2(); } else { VMW0(); }
                SBAR();                        // tile t fully landed, collectively
            }
            // ds-load this phase's fragments (6 x ds_read_b128)
            const int cof = (((q * 2 + kh5) ^ sw) << 3);
            short8 aF[4], bF[2];
#pragma unroll
            for (int fm = 0; fm < 4; fm++)
                aF[fm] = *(const short8*)&Ab[(wm + fm * 32 + l31) * BK + cof];
#pragma unroll
            for (int fn = 0; fn < 2; fn++)
                bF[fn] = *(const short8*)&Bb[(wn + fn * 32 + l31) * BK + cof];
            if (q > 0 && pre) STG1(t + 1, q, b ^ 1);
            SBAR();
            LGKM0(); SCHED0();
            __builtin_amdgcn_s_setprio(1);
#pragma unroll
            for (int fm = 0; fm < 4; fm++)
#pragma unroll
                for (int fn = 0; fn < 2; fn++)
                    acc[fm][fn] = __builtin_amdgcn_mfma_f32_32x32x16_bf16(
                        aF[fm], bF[fn], acc[fm][fn], 0, 0, 0);
            __builtin_amdgcn_s_setprio(0);
            SBAR();
        }
    }
#undef STG1

    // C/D: col = lane&31, row = (reg&3) + 8*(reg>>2) + 4*(lane>>5)
    const int obase = off[e] + m0;
#pragma unroll
    for (int fm = 0; fm < 4; fm++) {
#pragma unroll
        for (int reg = 0; reg < 16; reg++) {
            const int r32 = (reg & 3) + 8 * (reg >> 2) + 4 * kh5;
            const int rl = wm + fm * 32 + r32;
            if (m0 + rl < mpad) {              // 256-tile may cross 128-granular pad
                int ci = m0 + rl; if (ci >= ce) ci = ce - 1;
                const int tok = list[e * T_ + ci];
                const float pv = probs[(size_t)tok * E_ + e];
#pragma unroll
                for (int fn = 0; fn < 2; fn++) {
                    const int col = n0 + wn + fn * 32 + l31;
                    const float v = acc[fm][fn][reg];
                    // tanh-gelu via sigmoid: 0.5(1+tanh(u)) = sigma(2u)
                    const float u = 0.7978845608028654f * v * (1.0f + 0.044715f * v * v);
                    const float g = v / (1.0f + __expf(-2.0f * u));
                    Ag[(size_t)(obase + rl) * F_ + col] = __float2bfloat16(g * pv);
                }
            }
        }
    }
}

// GEMM2 (gathered, split-K=KSPLIT, no atomics):
// Y[ks][off[e]+i][h] = (Ag_e @ W2_e)[i][h] over k in [ks*KS,(ks+1)*KS)
// B-panel = W2t[e][h][f]: row stride F*2B = 8KB -> 128-row tile spans 1 MB.
__global__ __launch_bounds__(256)
void gemm2_kernel(const __hip_bfloat16* __restrict__ Ag,
                  const __hip_bfloat16* __restrict__ W2t,
                  const int* __restrict__ cnt, const int* __restrict__ off,
                  __hip_bfloat16* __restrict__ Y) {
    const int e  = blockIdx.z >> 2, kh = blockIdx.z & 3;
    const int ce = cnt[e];
    const int m0 = blockIdx.y * BM;
    if (m0 >= ce) return;
    const int n0 = blockIdx.x * BN;   // over H
    const int oe = off[e];
    __shared__ __align__(16) __hip_bfloat16 As[BM * BK];
    __shared__ __align__(16) __hip_bfloat16 Bs[BN * BK];
    const int tid = threadIdx.x, lane = tid & 63, wave = tid >> 6;
    const int wm = (wave >> 1) * 64, wn = (wave & 1) * 64;
    const int lr  = lane >> 3;
    const int lcg = ((lane & 7) ^ lr) * 8;
    const __hip_bfloat16* Abase = Ag + (size_t)oe * F_ + kh * KS;
    const __hip_bfloat16* Bbase = W2t + (size_t)e * F_ * H_ + kh * KS;

    f32x16 acc[2][2];
#pragma unroll
    for (int mi = 0; mi < 2; mi++)
#pragma unroll
        for (int ni = 0; ni < 2; ni++)
#pragma unroll
            for (int r = 0; r < 16; r++) acc[mi][ni][r] = 0.f;

    const int l31 = lane & 31, kh5 = lane >> 5, sw = lane & 7;

    for (int k0 = 0; k0 < KS; k0 += BK) {
#pragma unroll
        for (int j = 0; j < 4; j++) {
            const int i = wave * 4 + j;
            const int r = i * 8 + lr;
            async_copy16(Abase + (size_t)(m0 + r) * F_ + (k0 + lcg), (char*)As + i * 1024);
            async_copy16(Bbase + (size_t)(n0 + r) * F_ + (k0 + lcg), (char*)Bs + i * 1024);
        }
        __syncthreads();
#pragma unroll
        for (int ks = 0; ks < 4; ks++) {
            const int kq = ks * 2 + kh5;
            short8 aF[2], bF[2];
#pragma unroll
            for (int mi = 0; mi < 2; mi++)
                aF[mi] = *(const short8*)&As[(wm + mi * 32 + l31) * BK + ((kq ^ sw) << 3)];
#pragma unroll
            for (int ni = 0; ni < 2; ni++)
                bF[ni] = *(const short8*)&Bs[(wn + ni * 32 + l31) * BK + ((kq ^ sw) << 3)];
#pragma unroll
            for (int mi = 0; mi < 2; mi++)
#pragma unroll
                for (int ni = 0; ni < 2; ni++)
                    acc[mi][ni] = __builtin_amdgcn_mfma_f32_32x32x16_bf16(
                        aF[mi], bF[ni], acc[mi][ni], 0, 0, 0);
        }
        __syncthreads();
    }
    __hip_bfloat16* Yk = Y + (size_t)kh * ROWCAP * H_ + (size_t)(oe + m0) * H_;
#pragma unroll
    for (int mi = 0; mi < 2; mi++)
#pragma unroll
        for (int reg = 0; reg < 16; reg++) {
            const int r32 = (reg & 3) + 8 * (reg >> 2) + 4 * kh5;
            const int rl = wm + mi * 32 + r32;
#pragma unroll
            for (int ni = 0; ni < 2; ni++) {
                const int col = n0 + wn + ni * 32 + l31;
                Yk[(size_t)rl * H_ + col] = __float2bfloat16(acc[mi][ni][reg]);
            }
        }
}

// out[t][h] = res[t][h] + sum_{e routed} sum_{ks} Y[ks][off[e]+slot[t][e]][h]
__global__ __launch_bounds__(256)
void combine_kernel(const float* __restrict__ res, const float* __restrict__ probs,
                    const int* __restrict__ off, const int* __restrict__ slot,
                    const __hip_bfloat16* __restrict__ Y, float* __restrict__ out) {
    const int idx = blockIdx.x * 256 + threadIdx.x;   // T_*(H_/4) threads
    const int t  = idx >> 8;
    const int hc = (idx & 255) * 4;
    const float4 r = ((const float4*)res)[idx];
    float s0 = r.x, s1 = r.y, s2 = r.z, s3 = r.w;
#pragma unroll
    for (int e = 0; e < E_; e++) {
        if (probs[(size_t)t * E_ + e] > 0.0f) {
            const int row = off[e] + slot[(size_t)t * E_ + e];
#pragma unroll
            for (int ks = 0; ks < KSPLIT; ks++) {
                const ushort4 y = *(const ushort4*)&Y[((size_t)ks * ROWCAP + row) * H_ + hc];
                s0 += bf2f(y.x); s1 += bf2f(y.y); s2 += bf2f(y.z); s3 += bf2f(y.w);
            }
        }
    }
    ((float4*)out)[idx] = make_float4(s0, s1, s2, s3);
}

extern "C" void kernel_launch(void* const* d_in, const int* in_sizes, int n_in,
                              void* d_out, int out_size, void* d_ws, size_t ws_size,
                              hipStream_t stream) {
    const float* x     = (const float*)d_in[0];
    const float* res   = (const float*)d_in[1];
    const float* probs = (const float*)d_in[2];
    const float* w1    = (const float*)d_in[4];
    const float* w2    = (const float*)d_in[5];
    float* out = (float*)d_out;

    char* ws = (char*)d_ws;
    // Y (36 MiB) ALIASES Xb+W1t: both are dead after gemm1, and gemm2 (writes Y)
    // runs after gemm1 in stream order. Every call rewrites Xb/W1t before gemm1.
    __hip_bfloat16* Y   = (__hip_bfloat16*)(ws);                 // 36 MiB (KSPLIT slices)
    __hip_bfloat16* Xb  = (__hip_bfloat16*)(ws);                 //  4 MiB (dead after gemm1)
    __hip_bfloat16* W1t = (__hip_bfloat16*)(ws + (4ull  << 20)); // 32 MiB (dead after gemm1)
    __hip_bfloat16* W2t = (__hip_bfloat16*)(ws + (36ull << 20)); // 32 MiB
    __hip_bfloat16* Ag  = (__hip_bfloat16*)(ws + (68ull << 20)); // 36 MiB
    char* meta = ws + (104ull << 20);
    int* cnt  = (int*)meta;                       // 4 ints
    int* off  = (int*)(meta + 64);                // 5 ints
    int* list = (int*)(meta + 256);               // E*T ints = 32 KB
    int* slot = (int*)(meta + 256 + 4 * T_ * 4);  // T*E ints = 32 KB

    // 128 KiB dynamic LDS opt-in (idempotent, host-side, graph-capture safe).
    static bool s_attr = false;
    if (!s_attr) {
        hipFuncSetAttribute(reinterpret_cast<const void*>(gemm1_kernel),
                            hipFuncAttributeMaxDynamicSharedMemorySize, 131072);
        s_attr = true;
    }

    // 4 graph nodes: prep (W1 + X/routing), gemm1 (8-phase 256² + fused W2
    // transpose), gemm2 (128²), combine.
    trans_kernel<<<dim3(64, 16, E_ + 1), dim3(256), 0, stream>>>(
        w1, x, probs, W1t, Xb, cnt, off, list, slot);
    gemm1_kernel<<<dim3(F_ / BN1, T_ / BM1, E_ + 1), dim3(512), 131072, stream>>>(
        Xb, W1t, probs, cnt, off, list, Ag, w2, W2t);
    gemm2_kernel<<<dim3(H_ / BN, T_ / BM, KSPLIT * E_), dim3(256), 0, stream>>>(
        Ag, W2t, cnt, off, Y);
    combine_kernel<<<dim3(T_ * (H_ / 4) / 256), dim3(256), 0, stream>>>(
        res, probs, off, slot, Y, out);
}